// Round 3
// baseline (307.683 us; speedup 1.0000x reference)
//
#include <hip/hip_runtime.h>

#define B_ 16
#define S_ 20
#define L_ 64
#define T_ 1280
#define H_ 768
#define NITEMS 50000
#define TEMP 0.05f
#define EPSN 1e-8f

#define BM 320
#define BN 64
#define BK 32
#define NKT (H_ / BK)  // 24

typedef __attribute__((ext_vector_type(8))) short short8;
typedef __attribute__((ext_vector_type(4))) short short4v;
typedef __attribute__((ext_vector_type(4))) float f32x4;

__device__ __forceinline__ unsigned short f2bf(float f) {
    unsigned int u = __float_as_uint(f);
    u = u + 0x7FFFu + ((u >> 16) & 1u);
    return (unsigned short)(u >> 16);
}

typedef __attribute__((address_space(3))) void lds_void;
typedef const __attribute__((address_space(1))) void gbl_void;
__device__ __forceinline__ void load_lds16(const void* g, void* l) {
    __builtin_amdgcn_global_load_lds((gbl_void*)g, (lds_void*)l, 16, 0, 0);
}

// ---------------------------------------------------------------------------
// Kernel 1: per-(b,s) nan-mean pool, normalize, fold 1/(pn*TEMP), write bf16.
// ---------------------------------------------------------------------------
__global__ __launch_bounds__(192) void pool_kernel(const float* __restrict__ hidden,
                                                   const int* __restrict__ pos,
                                                   unsigned short* __restrict__ A,
                                                   int* __restrict__ valid) {
    const int row = blockIdx.x;  // 0..319
    const int b = row / S_, s = row % S_;
    const int tid = threadIdx.x;  // owns 4 consecutive h-cols

    __shared__ float wgt[L_];
    __shared__ int cntS;
    __shared__ float red[3];

    const int* pbase = pos + b * T_ + s * L_;
    if (tid < L_) {
        const int match = (pbase[tid] == s + 1) ? 1 : 0;
        unsigned long long bal = __ballot(match);
        wgt[tid] = match ? 1.0f : 0.0f;
        if (tid == 0) cntS = (int)__popcll(bal);
    }
    __syncthreads();

    const int cnt = cntS;
    const float inv = 1.0f / (float)(cnt > 0 ? cnt : 1);
    const float* hbase = hidden + ((size_t)b * T_ + (size_t)s * L_) * H_ + tid * 4;

    float a0 = 0.f, a1 = 0.f, a2 = 0.f, a3 = 0.f;
#pragma unroll 8
    for (int t = 0; t < L_; ++t) {
        const float w = wgt[t];
        const float4 v = *reinterpret_cast<const float4*>(hbase + (size_t)t * H_);
        a0 += w * v.x; a1 += w * v.y; a2 += w * v.z; a3 += w * v.w;
    }
    a0 *= inv; a1 *= inv; a2 *= inv; a3 *= inv;

    float ss = a0 * a0 + a1 * a1 + a2 * a2 + a3 * a3;
#pragma unroll
    for (int off = 32; off; off >>= 1) ss += __shfl_xor(ss, off, 64);
    const int wave = tid >> 6, lane = tid & 63;
    if (lane == 0) red[wave] = ss;
    __syncthreads();
    const float tot = red[0] + red[1] + red[2];
    const float scale = 1.0f / (fmaxf(sqrtf(tot), EPSN) * TEMP);

    short4v w4;
    w4[0] = (short)f2bf(a0 * scale);
    w4[1] = (short)f2bf(a1 * scale);
    w4[2] = (short)f2bf(a2 * scale);
    w4[3] = (short)f2bf(a3 * scale);
    *reinterpret_cast<short4v*>(A + (size_t)row * H_ + tid * 4) = w4;
    if (tid == 0) valid[row] = (cnt > 0) ? 1 : 0;
}

// ---------------------------------------------------------------------------
// Kernel 2: full-M GEMM, M split across waves. BM=320, BN=64, BK=32.
// Block: 4 waves; wave w owns A rows [80w, 80w+80): acc[5][4] f32x4 = 80 AGPR
// (vs 160 last round -> 2 waves/SIMD instead of 1). A staged bf16 via
// global_load_lds (dbuf). B staged via registers: fp32 global->reg, rowSq
// in-reg (en free), cvt->bf16, one ds_write_b128 -> Bs is bf16 (dbuf).
// One barrier per kt.
// ---------------------------------------------------------------------------
__global__ __launch_bounds__(256, 2) void gemm_kernel(const float* __restrict__ emb,
                                                      const unsigned short* __restrict__ A,
                                                      const int* __restrict__ valid,
                                                      float* __restrict__ out) {
    const int n0 = blockIdx.x * BN;
    const int tid = threadIdx.x;
    const int wave = tid >> 6, lane = tid & 63, quad = lane >> 4, lq = lane & 15;

    __shared__ alignas(16) short As[2][BM * BK];  // 2 x 20 KB bf16
    __shared__ alignas(16) short Bs[2][BN * BK];  // 2 x 4 KB bf16
    __shared__ float sEn[BN];
    __shared__ int sMask[B_];

    if (tid < B_) {
        int m = 0;
        for (int s = 0; s < S_; ++s) m |= (valid[tid * S_ + s] ? 1 : 0) << s;
        sMask[tid] = m;
    }

    // A staging: 5 glds issues; issue i covers rows (tid>>2)+64i, cols (tid&3)*8
    const unsigned short* aSrc = A + (size_t)(tid >> 2) * H_ + (tid & 3) * 8;

    // B staging via regs: thread owns row tid>>2, cols (tid&3)*8 .. +8 (2 float4)
    const int bRow = tid >> 2, bCol = (tid & 3) * 8;
    int gr = n0 + bRow;
    if (gr > NITEMS - 1) gr = NITEMS - 1;  // clamp; OOB cols never stored
    const float* bPtr = emb + (size_t)gr * H_ + bCol;
    const int bLds = bRow * BK + bCol;  // element offset in Bs

    // ---- prologue ----
#pragma unroll
    for (int i = 0; i < 5; ++i)
        load_lds16(aSrc + i * 64 * H_, (char*)(&As[0][0]) + tid * 16 + i * 4096);

    float rowSq = 0.f;
    float4 c0 = *reinterpret_cast<const float4*>(bPtr);
    float4 c1 = *reinterpret_cast<const float4*>(bPtr + 4);
    {   // tile 0 -> Bs[0]
        rowSq += c0.x * c0.x + c0.y * c0.y + c0.z * c0.z + c0.w * c0.w;
        rowSq += c1.x * c1.x + c1.y * c1.y + c1.z * c1.z + c1.w * c1.w;
        short8 w;
        w[0] = (short)f2bf(c0.x); w[1] = (short)f2bf(c0.y);
        w[2] = (short)f2bf(c0.z); w[3] = (short)f2bf(c0.w);
        w[4] = (short)f2bf(c1.x); w[5] = (short)f2bf(c1.y);
        w[6] = (short)f2bf(c1.z); w[7] = (short)f2bf(c1.w);
        *reinterpret_cast<short8*>(&Bs[0][bLds]) = w;
    }
    // regs for tile 1
    c0 = *reinterpret_cast<const float4*>(bPtr + BK);
    c1 = *reinterpret_cast<const float4*>(bPtr + BK + 4);

    f32x4 acc[5][4];
#pragma unroll
    for (int i = 0; i < 5; ++i)
#pragma unroll
        for (int j = 0; j < 4; ++j) acc[i][j] = (f32x4)0.f;

    int cur = 0;
    for (int kt = 0; kt < NKT; ++kt) {
        __syncthreads();  // A(kt) glds + B(kt) ds_write complete; prev reads done
        if (kt + 1 < NKT) {
            const int k0 = (kt + 1) * BK;
#pragma unroll
            for (int i = 0; i < 5; ++i)
                load_lds16(aSrc + k0 + i * 64 * H_,
                           (char*)(&As[cur ^ 1][0]) + tid * 16 + i * 4096);
            // cvt staged regs -> Bs[cur^1]; accumulate en
            rowSq += c0.x * c0.x + c0.y * c0.y + c0.z * c0.z + c0.w * c0.w;
            rowSq += c1.x * c1.x + c1.y * c1.y + c1.z * c1.z + c1.w * c1.w;
            short8 w;
            w[0] = (short)f2bf(c0.x); w[1] = (short)f2bf(c0.y);
            w[2] = (short)f2bf(c0.z); w[3] = (short)f2bf(c0.w);
            w[4] = (short)f2bf(c1.x); w[5] = (short)f2bf(c1.y);
            w[6] = (short)f2bf(c1.z); w[7] = (short)f2bf(c1.w);
            *reinterpret_cast<short8*>(&Bs[cur ^ 1][bLds]) = w;
            if (kt + 2 < NKT) {
                c0 = *reinterpret_cast<const float4*>(bPtr + (kt + 2) * BK);
                c1 = *reinterpret_cast<const float4*>(bPtr + (kt + 2) * BK + 4);
            }
        }

        // B fragments (shared by all waves): 4 x ds_read_b128
        short8 bF[4];
#pragma unroll
        for (int nf = 0; nf < 4; ++nf)
            bF[nf] = *reinterpret_cast<const short8*>(&Bs[cur][(nf * 16 + lq) * BK + quad * 8]);

        // A fragments (wave-private rows) + MFMA
#pragma unroll
        for (int mf = 0; mf < 5; ++mf) {
            const short8 aF = *reinterpret_cast<const short8*>(
                &As[cur][(wave * 80 + mf * 16 + lq) * BK + quad * 8]);
#pragma unroll
            for (int nf = 0; nf < 4; ++nf)
                acc[mf][nf] = __builtin_amdgcn_mfma_f32_16x16x32_bf16(aF, bF[nf], acc[mf][nf], 0, 0, 0);
        }
        cur ^= 1;
    }

    // finalize en: reduce the 4 threads of each B row
    rowSq += __shfl_xor(rowSq, 1, 64);
    rowSq += __shfl_xor(rowSq, 2, 64);
    if ((tid & 3) == 0) sEn[bRow] = fmaxf(sqrtf(rowSq), EPSN);
    __syncthreads();

    // epilogue: wave w holds sessions [4w,4w+4); masked max over 20 rows each
#pragma unroll
    for (int nf = 0; nf < 4; ++nf) {
        const int ncol = nf * 16 + lq;
        const int n = n0 + ncol;
        const float inv_en = 1.0f / sEn[ncol];
#pragma unroll
        for (int bb = 0; bb < 4; ++bb) {
            const int rLo = bb * S_;          // row offset within the wave's 80
            const int msk = sMask[wave * 4 + bb];
            const int mfLo = rLo >> 4;
            const int mfHi = (rLo + S_ - 1) >> 4;
            float lm = -__builtin_inff();
#pragma unroll
            for (int mf = mfLo; mf <= mfHi; ++mf)
#pragma unroll
                for (int e = 0; e < 4; ++e) {
                    const int r = mf * 16 + quad * 4 + e;
                    const unsigned off = (unsigned)(r - rLo);
                    const bool ok = (off < (unsigned)S_) && ((msk >> off) & 1);
                    lm = ok ? fmaxf(lm, acc[mf][nf][e]) : lm;
                }
            lm = fmaxf(lm, __shfl_xor(lm, 16, 64));
            lm = fmaxf(lm, __shfl_xor(lm, 32, 64));
            if (quad == 0 && n < NITEMS)
                out[(size_t)(wave * 4 + bb) * NITEMS + n] = lm * inv_en;
        }
    }
}

extern "C" void kernel_launch(void* const* d_in, const int* in_sizes, int n_in,
                              void* d_out, int out_size, void* d_ws, size_t ws_size,
                              hipStream_t stream) {
    const float* hidden = (const float*)d_in[0];   // [16,1280,768] f32
    const float* emb    = (const float*)d_in[1];   // [50000,768] f32
    const int*   pos    = (const int*)d_in[3];     // [16,1280] i32
    float* out = (float*)d_out;                    // [16,50000] f32

    unsigned short* Abf = (unsigned short*)d_ws;               // 320*768 bf16
    int* valid = (int*)((char*)d_ws + (size_t)320 * 768 * 2);  // 320 ints

    pool_kernel<<<dim3(320), dim3(192), 0, stream>>>(hidden, pos, Abf, valid);
    gemm_kernel<<<dim3((NITEMS + BN - 1) / BN), dim3(256), 0, stream>>>(emb, Abf, valid, out);
}